// Round 11
// baseline (389.200 us; speedup 1.0000x reference)
//
#include <hip/hip_runtime.h>
#include <math.h>

#define N_NODES  50000
#define N_EDGES  800000
#define FDIM     128
#define N_GRAPHS 500
#define NEG_SLOPE 0.2f
#define EN_TOTAL (N_EDGES + N_NODES)
#define SCAN_NB ((N_NODES + 255) / 256)   // 196
#define GEMM_TILES (N_NODES / 16)         // 3125 exact
#define WT_COLS 144                        // 128 + [wa_src, wa_dst, 14 zero]

typedef short bf16x8 __attribute__((ext_vector_type(8)));
typedef float f32x4 __attribute__((ext_vector_type(4)));

// A-plane fragment layout: slot(tile, cc, p, lane) of 16B (8 bf16):
//   idx16B = ((tile*8 + cc*2 + p)*64 + lane),  lane = g*16 + r16
//   holds node row = tile*16 + r16, feats k = cc*32 + g*8 .. +8, plane p (0=hi,1=lo)

static __device__ __forceinline__ float lrelu(float x) {
    return x >= 0.f ? x : NEG_SLOPE * x;
}
static __device__ __forceinline__ unsigned short f2bf(float v) {
    unsigned int u = __float_as_uint(v);
    u += 0x7fffu + ((u >> 16) & 1u);
    return (unsigned short)(u >> 16);
}
static __device__ __forceinline__ float bf2f(unsigned short s) {
    return __uint_as_float(((unsigned int)s) << 16);
}

// ---------------- split X fp32 -> fragment-ordered bf16 hi/lo planes ----------
__global__ __launch_bounds__(256) void prep_planes(
    const float* __restrict__ X, unsigned short* __restrict__ Abuf)
{
    const int i = blockIdx.x * 256 + threadIdx.x;   // one thread per (tile,cc,lane)
    if (i >= GEMM_TILES * 4 * 64) return;
    const int tile = i >> 8, rem = i & 255;
    const int cc = rem >> 6, lane = rem & 63;
    const int r16 = lane & 15, g = lane >> 4;
    const int row = tile * 16 + r16;
    const int k0 = cc * 32 + g * 8;

    const float4 v0 = *(const float4*)(X + (size_t)row * FDIM + k0);
    const float4 v1 = *(const float4*)(X + (size_t)row * FDIM + k0 + 4);
    const float vv[8] = {v0.x, v0.y, v0.z, v0.w, v1.x, v1.y, v1.z, v1.w};
    unsigned short h8[8], l8[8];
    #pragma unroll
    for (int e = 0; e < 8; ++e) {
        h8[e] = f2bf(vv[e]);
        l8[e] = f2bf(vv[e] - bf2f(h8[e]));
    }
    const size_t base = ((size_t)(tile * 8 + cc * 2) * 64 + lane) * 8;
    *(uint4*)(Abuf + base)            = *(const uint4*)h8;
    *(uint4*)(Abuf + base + 64 * 8)   = *(const uint4*)l8;
}

// ---- W -> transposed bf16 hi/lo planes [c][k], c in [0,144):
//      cols 0..127 = W^T; col 128 = W@a_src; col 129 = W@a_dst; 130..143 = 0.
__global__ __launch_bounds__(256) void prep_wt(
    const float* __restrict__ W0, const float* __restrict__ W1,
    const float* __restrict__ W2,
    const float* __restrict__ as0, const float* __restrict__ as1,
    const float* __restrict__ as2,
    const float* __restrict__ ad0, const float* __restrict__ ad1,
    const float* __restrict__ ad2,
    unsigned short* __restrict__ WT)
{
    const int l = blockIdx.x;
    const float* W  = (l == 0) ? W0  : (l == 1) ? W1  : W2;
    const float* As = (l == 0) ? as0 : (l == 1) ? as1 : as2;
    const float* Ad = (l == 0) ? ad0 : (l == 1) ? ad1 : ad2;
    unsigned short* hi = WT + (size_t)l * 2 * WT_COLS * FDIM;
    unsigned short* lo = hi + WT_COLS * FDIM;
    const int tid = threadIdx.x;

    __shared__ float wa[256];   // [0..127] = (W a_src)[k], [128..255] = (W a_dst)[k]
    {
        const int k = tid & 127;
        const float* av = (tid < 128) ? As : Ad;
        float s = 0.f;
        for (int c = 0; c < 128; ++c) s += W[k * FDIM + c] * av[c];
        wa[tid] = s;
    }
    __syncthreads();

    for (int i = tid; i < FDIM * FDIM; i += 256) {
        const int k = i >> 7, c = i & 127;
        const float v = W[i];
        const unsigned short h = f2bf(v);
        hi[c * FDIM + k] = h;
        lo[c * FDIM + k] = f2bf(v - bf2f(h));
    }
    for (int k = tid; k < FDIM; k += 256) {
        const float vs = wa[k], vd = wa[128 + k];
        const unsigned short hs = f2bf(vs), hd = f2bf(vd);
        hi[128 * FDIM + k] = hs; lo[128 * FDIM + k] = f2bf(vs - bf2f(hs));
        hi[129 * FDIM + k] = hd; lo[129 * FDIM + k] = f2bf(vd - bf2f(hd));
    }
    for (int i = tid; i < 14 * FDIM; i += 256) {
        hi[130 * FDIM + i] = 0;
        lo[130 * FDIM + i] = 0;
    }
}

// ---------------- h = X @ W, persistent-B MFMA, coalesced fragment A-loads ----
// 4 waves/block, wave owns col-tiles {2wv,2wv+1}; B frags persistent (64 VGPR).
// A-loads: lane-consecutive 16B from fragment-ordered Abuf -> 1KB/inst coalesced.
// Rotating duty wave computes extra tile (cols 128/129 = asrc/adst).
__global__ __launch_bounds__(256) void gemm_mfma5(
    const unsigned short* __restrict__ Abuf,
    const unsigned short* __restrict__ WThi, const unsigned short* __restrict__ WTlo,
    unsigned short* __restrict__ Hb, float* __restrict__ asrcN, float* __restrict__ adstN)
{
    const int tid = threadIdx.x, wv = tid >> 6, lane = tid & 63;
    const int r16 = lane & 15, g = lane >> 4;
    const int t0 = wv * 2;

    bf16x8 bh[2][4], bl[2][4];
    #pragma unroll
    for (int tt = 0; tt < 2; ++tt) {
        const int c = (t0 + tt) * 16 + r16;
        #pragma unroll
        for (int cc = 0; cc < 4; ++cc) {
            bh[tt][cc] = *(const bf16x8*)(WThi + c * FDIM + cc * 32 + 8 * g);
            bl[tt][cc] = *(const bf16x8*)(WTlo + c * FDIM + cc * 32 + 8 * g);
        }
    }
    const unsigned short* WThiE = WThi + (128 + r16) * FDIM + 8 * g;
    const unsigned short* WTloE = WTlo + (128 + r16) * FDIM + 8 * g;

    int rot = 0;
    for (int tile = blockIdx.x; tile < GEMM_TILES; tile += gridDim.x, ++rot) {
        const int m0 = tile * 16;
        const bf16x8* At = (const bf16x8*)Abuf + (size_t)tile * 512 + lane;

        bf16x8 ah[4], al[4];
        #pragma unroll
        for (int cc = 0; cc < 4; ++cc) {
            ah[cc] = At[cc * 128];
            al[cc] = At[cc * 128 + 64];
        }

        f32x4 acc0 = {0.f, 0.f, 0.f, 0.f}, acc1 = {0.f, 0.f, 0.f, 0.f};
        #pragma unroll
        for (int cc = 0; cc < 4; ++cc) {
            acc0 = __builtin_amdgcn_mfma_f32_16x16x32_bf16(ah[cc], bh[0][cc], acc0, 0, 0, 0);
            acc1 = __builtin_amdgcn_mfma_f32_16x16x32_bf16(ah[cc], bh[1][cc], acc1, 0, 0, 0);
            acc0 = __builtin_amdgcn_mfma_f32_16x16x32_bf16(al[cc], bh[0][cc], acc0, 0, 0, 0);
            acc1 = __builtin_amdgcn_mfma_f32_16x16x32_bf16(al[cc], bh[1][cc], acc1, 0, 0, 0);
            acc0 = __builtin_amdgcn_mfma_f32_16x16x32_bf16(ah[cc], bl[0][cc], acc0, 0, 0, 0);
            acc1 = __builtin_amdgcn_mfma_f32_16x16x32_bf16(ah[cc], bl[1][cc], acc1, 0, 0, 0);
        }

        const int rowb = m0 + 4 * g;
        #pragma unroll
        for (int r = 0; r < 4; ++r) {
            Hb[(size_t)(rowb + r) * FDIM + (t0 + 0) * 16 + r16] = f2bf(acc0[r]);
            Hb[(size_t)(rowb + r) * FDIM + (t0 + 1) * 16 + r16] = f2bf(acc1[r]);
        }

        if (wv == ((tile + rot) & 3)) {
            f32x4 acce = {0.f, 0.f, 0.f, 0.f};
            #pragma unroll
            for (int cc = 0; cc < 4; ++cc) {
                const bf16x8 bhe = *(const bf16x8*)(WThiE + cc * 32);
                const bf16x8 ble = *(const bf16x8*)(WTloE + cc * 32);
                acce = __builtin_amdgcn_mfma_f32_16x16x32_bf16(ah[cc], bhe, acce, 0, 0, 0);
                acce = __builtin_amdgcn_mfma_f32_16x16x32_bf16(al[cc], bhe, acce, 0, 0, 0);
                acce = __builtin_amdgcn_mfma_f32_16x16x32_bf16(ah[cc], ble, acce, 0, 0, 0);
            }
            if (r16 == 0) {
                #pragma unroll
                for (int r = 0; r < 4; ++r) asrcN[rowb + r] = acce[r];
            } else if (r16 == 1) {
                #pragma unroll
                for (int r = 0; r < 4; ++r) adstN[rowb + r] = acce[r];
            }
        }
    }
}

// ---------------- CSR build ----------------
__global__ void count_edges(const int* __restrict__ ei, int* __restrict__ cnt) {
    int i = blockIdx.x * 256 + threadIdx.x;
    if (i < EN_TOTAL) {
        int d = (i < N_EDGES) ? ei[N_EDGES + i] : (i - N_EDGES);
        atomicAdd(&cnt[d], 1);
    }
}

__global__ __launch_bounds__(256) void scan_block(const int* __restrict__ cnt,
                                                  int* __restrict__ off,
                                                  int* __restrict__ blockSums) {
    __shared__ int s[256];
    const int i = blockIdx.x * 256 + threadIdx.x;
    s[threadIdx.x] = (i < N_NODES) ? cnt[i] : 0;
    __syncthreads();
    #pragma unroll
    for (int d = 1; d < 256; d <<= 1) {
        int t = (threadIdx.x >= d) ? s[threadIdx.x - d] : 0;
        __syncthreads();
        s[threadIdx.x] += t;
        __syncthreads();
    }
    if (i < N_NODES) off[i + 1] = s[threadIdx.x];
    if (threadIdx.x == 255) blockSums[blockIdx.x] = s[255];
}

__global__ __launch_bounds__(256) void scan_sums(int* __restrict__ blockSums) {
    __shared__ int s[256];
    s[threadIdx.x] = (threadIdx.x < SCAN_NB) ? blockSums[threadIdx.x] : 0;
    __syncthreads();
    #pragma unroll
    for (int d = 1; d < 256; d <<= 1) {
        int t = (threadIdx.x >= d) ? s[threadIdx.x - d] : 0;
        __syncthreads();
        s[threadIdx.x] += t;
        __syncthreads();
    }
    if (threadIdx.x < SCAN_NB)
        blockSums[threadIdx.x] = (threadIdx.x == 0) ? 0 : s[threadIdx.x - 1];
}

__global__ __launch_bounds__(256) void add_base(int* __restrict__ off,
                                                const int* __restrict__ blockSums) {
    const int i = blockIdx.x * 256 + threadIdx.x;
    if (i < N_NODES) off[i + 1] += blockSums[blockIdx.x];
    if (i == 0) off[0] = 0;
}

__global__ void scatter_edges(const int* __restrict__ ei, const int* __restrict__ off,
                              int* __restrict__ cur, int* __restrict__ srcs) {
    int i = blockIdx.x * 256 + threadIdx.x;
    if (i < EN_TOTAL) {
        int s, d;
        if (i < N_EDGES) { s = ei[i]; d = ei[N_EDGES + i]; }
        else             { s = d = i - N_EDGES; }
        int p = off[d] + atomicAdd(&cur[d], 1);
        srcs[p] = s;
    }
}

// ---------------- segment softmax + weighted aggregation (bf16 H gather) -------
// mode 0: relu + write fragment-ordered hi/lo planes (next layer's gemm input)
// mode 1: no relu + write fp32 row-major (pool input)
__global__ __launch_bounds__(256) void gat_aggregate(
    const unsigned short* __restrict__ Hb, const int* __restrict__ off,
    const int* __restrict__ srcs,
    const float* __restrict__ asrcN, const float* __restrict__ adstN,
    const float* __restrict__ bias,
    unsigned short* __restrict__ Abuf, float* __restrict__ OUTF, int mode)
{
    const int wave = threadIdx.x >> 6, lane = threadIdx.x & 63;
    const int grp = lane >> 3, fl = lane & 7;

    for (int n = blockIdx.x * 4 + wave; n < N_NODES; n += gridDim.x * 4) {
        const int s0 = off[n], s1 = off[n + 1];
        const int deg = s1 - s0;
        const float ad = adstN[n];

        float e_reg = -1e30f;
        float m = -1e30f;
        for (int j = s0 + lane; j < s1; j += 64) {
            float e = lrelu(asrcN[srcs[j]] + ad);
            if (j - s0 < 64) e_reg = e;
            m = fmaxf(m, e);
        }
        #pragma unroll
        for (int o = 32; o; o >>= 1) m = fmaxf(m, __shfl_xor(m, o));

        float4 a0 = {0,0,0,0}, a1 = {0,0,0,0}, a2 = {0,0,0,0}, a3 = {0,0,0,0};
        float dn = 0.f;
        const unsigned short* Hf = Hb + (size_t)fl * 16;
        for (int j = s0 + grp; j < s1; j += 8) {
            const int s = srcs[j];
            const float ex = (deg <= 64)
                ? __expf(__shfl(e_reg, j - s0) - m)
                : __expf(lrelu(asrcN[s] + ad) - m);
            dn += ex;
            const uint4* hp = (const uint4*)(Hf + (size_t)s * FDIM);
            const uint4 u0 = hp[0], u1 = hp[1];
            a0.x += ex * __uint_as_float(u0.x << 16);
            a0.y += ex * __uint_as_float(u0.x & 0xffff0000u);
            a0.z += ex * __uint_as_float(u0.y << 16);
            a0.w += ex * __uint_as_float(u0.y & 0xffff0000u);
            a1.x += ex * __uint_as_float(u0.z << 16);
            a1.y += ex * __uint_as_float(u0.z & 0xffff0000u);
            a1.z += ex * __uint_as_float(u0.w << 16);
            a1.w += ex * __uint_as_float(u0.w & 0xffff0000u);
            a2.x += ex * __uint_as_float(u1.x << 16);
            a2.y += ex * __uint_as_float(u1.x & 0xffff0000u);
            a2.z += ex * __uint_as_float(u1.y << 16);
            a2.w += ex * __uint_as_float(u1.y & 0xffff0000u);
            a3.x += ex * __uint_as_float(u1.z << 16);
            a3.y += ex * __uint_as_float(u1.z & 0xffff0000u);
            a3.z += ex * __uint_as_float(u1.w << 16);
            a3.w += ex * __uint_as_float(u1.w & 0xffff0000u);
        }

        #pragma unroll
        for (int o = 8; o <= 32; o <<= 1) {
            dn  += __shfl_xor(dn, o);
            a0.x += __shfl_xor(a0.x, o); a0.y += __shfl_xor(a0.y, o);
            a0.z += __shfl_xor(a0.z, o); a0.w += __shfl_xor(a0.w, o);
            a1.x += __shfl_xor(a1.x, o); a1.y += __shfl_xor(a1.y, o);
            a1.z += __shfl_xor(a1.z, o); a1.w += __shfl_xor(a1.w, o);
            a2.x += __shfl_xor(a2.x, o); a2.y += __shfl_xor(a2.y, o);
            a2.z += __shfl_xor(a2.z, o); a2.w += __shfl_xor(a2.w, o);
            a3.x += __shfl_xor(a3.x, o); a3.y += __shfl_xor(a3.y, o);
            a3.z += __shfl_xor(a3.z, o); a3.w += __shfl_xor(a3.w, o);
        }

        if (grp == 0) {
            const float rd = 1.f / dn;
            const float4* bp = (const float4*)(bias + fl * 16);
            float4 ov[4] = {a0, a1, a2, a3};
            float o16[16];
            #pragma unroll
            for (int q = 0; q < 4; ++q) {
                const float4 b4 = bp[q];
                float4 o4;
                o4.x = ov[q].x * rd + b4.x; o4.y = ov[q].y * rd + b4.y;
                o4.z = ov[q].z * rd + b4.z; o4.w = ov[q].w * rd + b4.w;
                if (mode == 0) {
                    o4.x = fmaxf(o4.x, 0.f); o4.y = fmaxf(o4.y, 0.f);
                    o4.z = fmaxf(o4.z, 0.f); o4.w = fmaxf(o4.w, 0.f);
                    o16[q * 4 + 0] = o4.x; o16[q * 4 + 1] = o4.y;
                    o16[q * 4 + 2] = o4.z; o16[q * 4 + 3] = o4.w;
                } else {
                    *(float4*)(OUTF + (size_t)n * FDIM + fl * 16 + q * 4) = o4;
                }
            }
            if (mode == 0) {
                // write fragment layout: tile=n>>4, r16=n&15, cc=fl>>1,
                // chunk jc: g=(fl&1)*2+jc, slot=((tile*8+cc*2+p)*64 + g*16 + r16)
                const int tile = n >> 4, r16 = n & 15, cc = fl >> 1;
                #pragma unroll
                for (int jc = 0; jc < 2; ++jc) {
                    unsigned short h8[8], l8[8];
                    #pragma unroll
                    for (int e = 0; e < 8; ++e) {
                        const float v = o16[jc * 8 + e];
                        h8[e] = f2bf(v);
                        l8[e] = f2bf(v - bf2f(h8[e]));
                    }
                    const int gslot = (fl & 1) * 2 + jc;
                    const size_t baseH = ((size_t)(tile * 8 + cc * 2 + 0) * 64 + gslot * 16 + r16) * 8;
                    const size_t baseL = ((size_t)(tile * 8 + cc * 2 + 1) * 64 + gslot * 16 + r16) * 8;
                    *(uint4*)(Abuf + baseH) = *(const uint4*)h8;
                    *(uint4*)(Abuf + baseL) = *(const uint4*)l8;
                }
            }
        }
    }
}

// ---------------- global mean pool + final linear (8 rows in flight) ----------
__global__ __launch_bounds__(256) void pool_linear2(
    const float* __restrict__ H, const int* __restrict__ batch,
    const float* __restrict__ Wlin, const float* __restrict__ blin,
    float* __restrict__ out)
{
    const int g = blockIdx.x, tid = threadIdx.x;
    const int rl = tid >> 5, fq = tid & 31;

    int a = 0, b = N_NODES;
    while (a < b) { int mid = (a + b) >> 1; if (batch[mid] < g) a = mid + 1; else b = mid; }
    const int lo = a;
    b = N_NODES;
    while (a < b) { int mid = (a + b) >> 1; if (batch[mid] <= g) a = mid + 1; else b = mid; }
    const int hi = a;

    float4 acc = {0.f, 0.f, 0.f, 0.f};
    for (int n = lo + rl; n < hi; n += 8) {
        const float4 v = *(const float4*)(H + (size_t)n * FDIM + fq * 4);
        acc.x += v.x; acc.y += v.y; acc.z += v.z; acc.w += v.w;
    }
    __shared__ float4 s[8][32];
    s[rl][fq] = acc;
    __syncthreads();

    if (tid < 32) {
        float4 t = s[0][fq];
        #pragma unroll
        for (int r = 1; r < 8; ++r) {
            const float4 v = s[r][fq];
            t.x += v.x; t.y += v.y; t.z += v.z; t.w += v.w;
        }
        const float inv = 1.f / fmaxf((float)(hi - lo), 1.f);
        t.x *= inv; t.y *= inv; t.z *= inv; t.w *= inv;
        float d0 = t.x * Wlin[(fq * 4 + 0) * 2 + 0] + t.y * Wlin[(fq * 4 + 1) * 2 + 0]
                 + t.z * Wlin[(fq * 4 + 2) * 2 + 0] + t.w * Wlin[(fq * 4 + 3) * 2 + 0];
        float d1 = t.x * Wlin[(fq * 4 + 0) * 2 + 1] + t.y * Wlin[(fq * 4 + 1) * 2 + 1]
                 + t.z * Wlin[(fq * 4 + 2) * 2 + 1] + t.w * Wlin[(fq * 4 + 3) * 2 + 1];
        #pragma unroll
        for (int o = 1; o <= 16; o <<= 1) {
            d0 += __shfl_xor(d0, o);
            d1 += __shfl_xor(d1, o);
        }
        if (fq == 0) {
            out[g * 2 + 0] = d0 + blin[0];
            out[g * 2 + 1] = d1 + blin[1];
        }
    }
}

extern "C" void kernel_launch(void* const* d_in, const int* in_sizes, int n_in,
                              void* d_out, int out_size, void* d_ws, size_t ws_size,
                              hipStream_t stream)
{
    const float* x     = (const float*)d_in[0];
    const int*   ei    = (const int*)d_in[1];
    const int*   batch = (const int*)d_in[2];
    const float* W[3]    = {(const float*)d_in[3],  (const float*)d_in[7],  (const float*)d_in[11]};
    const float* avs[3]  = {(const float*)d_in[4],  (const float*)d_in[8],  (const float*)d_in[12]};
    const float* avd[3]  = {(const float*)d_in[5],  (const float*)d_in[9],  (const float*)d_in[13]};
    const float* bias[3] = {(const float*)d_in[6],  (const float*)d_in[10], (const float*)d_in[14]};
    const float* Wlin = (const float*)d_in[15];
    const float* blin = (const float*)d_in[16];
    float* out = (float*)d_out;

    char* w = (char*)d_ws;
    unsigned short* Abuf = (unsigned short*)w; w += (size_t)N_NODES * FDIM * 4; // 25.6 MB (hi+lo frag)
    float* hOf = (float*)Abuf;                                                  // overlay (pool input)
    unsigned short* Hb = (unsigned short*)w; w += (size_t)N_NODES * FDIM * 2;   // 12.8 MB
    float* attn  = (float*)w; w += 2 * 200192;
    int*   off   = (int*)w;   w += 200192;
    int*   cnt   = (int*)w;   w += 200192;
    int*   bsum  = (int*)w;   w += 4096;
    int*   srcs  = (int*)w;   w += (size_t)EN_TOTAL * 4;
    unsigned short* WT = (unsigned short*)w; w += (size_t)3 * 2 * WT_COLS * FDIM * 2;  // 221 KB
    float* asrcN = attn;
    float* adstN = attn + N_NODES;

    // ---- preps ----
    prep_planes<<<(GEMM_TILES * 4 * 64 + 255) / 256, 256, 0, stream>>>(x, Abuf);
    prep_wt<<<3, 256, 0, stream>>>(W[0], W[1], W[2],
                                   avs[0], avs[1], avs[2],
                                   avd[0], avd[1], avd[2], WT);

    // ---- CSR by destination (topology shared across layers) ----
    hipMemsetAsync(cnt, 0, N_NODES * sizeof(int), stream);
    count_edges<<<(EN_TOTAL + 255) / 256, 256, 0, stream>>>(ei, cnt);
    scan_block<<<SCAN_NB, 256, 0, stream>>>(cnt, off, bsum);
    scan_sums<<<1, 256, 0, stream>>>(bsum);
    add_base<<<SCAN_NB, 256, 0, stream>>>(off, bsum);
    hipMemsetAsync(cnt, 0, N_NODES * sizeof(int), stream);
    scatter_edges<<<(EN_TOTAL + 255) / 256, 256, 0, stream>>>(ei, off, cnt, srcs);

    // ---- 3 GAT layers ----
    for (int l = 0; l < 3; ++l) {
        const unsigned short* WThi = WT + (size_t)l * 2 * WT_COLS * FDIM;
        const unsigned short* WTlo = WThi + WT_COLS * FDIM;
        gemm_mfma5<<<1024, 256, 0, stream>>>(Abuf, WThi, WTlo, Hb, asrcN, adstN);
        gat_aggregate<<<2048, 256, 0, stream>>>(Hb, off, srcs, asrcN, adstN, bias[l],
                                                Abuf, hOf, (l < 2) ? 0 : 1);
    }

    // ---- mean pool + linear ----
    pool_linear2<<<N_GRAPHS, 256, 0, stream>>>(hOf, batch, Wlin, blin, out);
}

// Round 12
// 357.596 us; speedup vs baseline: 1.0884x; 1.0884x over previous
//
#include <hip/hip_runtime.h>
#include <math.h>

#define N_NODES  50000
#define N_EDGES  800000
#define FDIM     128
#define N_GRAPHS 500
#define NEG_SLOPE 0.2f
#define EN_TOTAL (N_EDGES + N_NODES)
#define SCAN_NB ((N_NODES + 255) / 256)   // 196
#define GEMM_TILES (N_NODES / 16)         // 3125 exact
#define WT_COLS 144                        // 128 + [wa_src, wa_dst, 14 zero]

typedef short bf16x8 __attribute__((ext_vector_type(8)));
typedef float f32x4 __attribute__((ext_vector_type(4)));

// A-plane fragment layout: slot(tile, cc, p, lane) of 16B (8 bf16):
//   idx16B = ((tile*8 + cc*2 + p)*64 + lane),  lane = g*16 + r16
//   holds node row = tile*16 + r16, feats k = cc*32 + g*8 .. +8, plane p (0=hi,1=lo)

static __device__ __forceinline__ float lrelu(float x) {
    return x >= 0.f ? x : NEG_SLOPE * x;
}
static __device__ __forceinline__ unsigned short f2bf(float v) {
    unsigned int u = __float_as_uint(v);
    u += 0x7fffu + ((u >> 16) & 1u);
    return (unsigned short)(u >> 16);
}
static __device__ __forceinline__ float bf2f(unsigned short s) {
    return __uint_as_float(((unsigned int)s) << 16);
}

// ---------------- split X fp32 -> fragment-ordered bf16 hi/lo planes ----------
__global__ __launch_bounds__(256) void prep_planes(
    const float* __restrict__ X, unsigned short* __restrict__ Abuf)
{
    const int i = blockIdx.x * 256 + threadIdx.x;   // one thread per (tile,cc,lane)
    if (i >= GEMM_TILES * 4 * 64) return;
    const int tile = i >> 8, rem = i & 255;
    const int cc = rem >> 6, lane = rem & 63;
    const int r16 = lane & 15, g = lane >> 4;
    const int row = tile * 16 + r16;
    const int k0 = cc * 32 + g * 8;

    const float4 v0 = *(const float4*)(X + (size_t)row * FDIM + k0);
    const float4 v1 = *(const float4*)(X + (size_t)row * FDIM + k0 + 4);
    const float vv[8] = {v0.x, v0.y, v0.z, v0.w, v1.x, v1.y, v1.z, v1.w};
    unsigned short h8[8], l8[8];
    #pragma unroll
    for (int e = 0; e < 8; ++e) {
        h8[e] = f2bf(vv[e]);
        l8[e] = f2bf(vv[e] - bf2f(h8[e]));
    }
    const size_t base = ((size_t)(tile * 8 + cc * 2) * 64 + lane) * 8;
    *(uint4*)(Abuf + base)            = *(const uint4*)h8;
    *(uint4*)(Abuf + base + 64 * 8)   = *(const uint4*)l8;
}

// ---- W -> transposed bf16 hi/lo planes [c][k], c in [0,144):
//      cols 0..127 = W^T; col 128 = W@a_src; col 129 = W@a_dst; 130..143 = 0.
__global__ __launch_bounds__(256) void prep_wt(
    const float* __restrict__ W0, const float* __restrict__ W1,
    const float* __restrict__ W2,
    const float* __restrict__ as0, const float* __restrict__ as1,
    const float* __restrict__ as2,
    const float* __restrict__ ad0, const float* __restrict__ ad1,
    const float* __restrict__ ad2,
    unsigned short* __restrict__ WT)
{
    const int l = blockIdx.x;
    const float* W  = (l == 0) ? W0  : (l == 1) ? W1  : W2;
    const float* As = (l == 0) ? as0 : (l == 1) ? as1 : as2;
    const float* Ad = (l == 0) ? ad0 : (l == 1) ? ad1 : ad2;
    unsigned short* hi = WT + (size_t)l * 2 * WT_COLS * FDIM;
    unsigned short* lo = hi + WT_COLS * FDIM;
    const int tid = threadIdx.x;

    __shared__ float wa[256];   // [0..127] = (W a_src)[k], [128..255] = (W a_dst)[k]
    {
        const int k = tid & 127;
        const float* av = (tid < 128) ? As : Ad;
        float s = 0.f;
        for (int c = 0; c < 128; ++c) s += W[k * FDIM + c] * av[c];
        wa[tid] = s;
    }
    __syncthreads();

    for (int i = tid; i < FDIM * FDIM; i += 256) {
        const int k = i >> 7, c = i & 127;
        const float v = W[i];
        const unsigned short h = f2bf(v);
        hi[c * FDIM + k] = h;
        lo[c * FDIM + k] = f2bf(v - bf2f(h));
    }
    for (int k = tid; k < FDIM; k += 256) {
        const float vs = wa[k], vd = wa[128 + k];
        const unsigned short hs = f2bf(vs), hd = f2bf(vd);
        hi[128 * FDIM + k] = hs; lo[128 * FDIM + k] = f2bf(vs - bf2f(hs));
        hi[129 * FDIM + k] = hd; lo[129 * FDIM + k] = f2bf(vd - bf2f(hd));
    }
    for (int i = tid; i < 14 * FDIM; i += 256) {
        hi[130 * FDIM + i] = 0;
        lo[130 * FDIM + i] = 0;
    }
}

// ---------------- h = X @ W, persistent-B MFMA, coalesced fragment A-loads ----
__global__ __launch_bounds__(256) void gemm_mfma5(
    const unsigned short* __restrict__ Abuf,
    const unsigned short* __restrict__ WThi, const unsigned short* __restrict__ WTlo,
    unsigned short* __restrict__ Hb, float* __restrict__ asrcN, float* __restrict__ adstN)
{
    const int tid = threadIdx.x, wv = tid >> 6, lane = tid & 63;
    const int r16 = lane & 15, g = lane >> 4;
    const int t0 = wv * 2;

    bf16x8 bh[2][4], bl[2][4];
    #pragma unroll
    for (int tt = 0; tt < 2; ++tt) {
        const int c = (t0 + tt) * 16 + r16;
        #pragma unroll
        for (int cc = 0; cc < 4; ++cc) {
            bh[tt][cc] = *(const bf16x8*)(WThi + c * FDIM + cc * 32 + 8 * g);
            bl[tt][cc] = *(const bf16x8*)(WTlo + c * FDIM + cc * 32 + 8 * g);
        }
    }
    const unsigned short* WThiE = WThi + (128 + r16) * FDIM + 8 * g;
    const unsigned short* WTloE = WTlo + (128 + r16) * FDIM + 8 * g;

    int rot = 0;
    for (int tile = blockIdx.x; tile < GEMM_TILES; tile += gridDim.x, ++rot) {
        const int m0 = tile * 16;
        const bf16x8* At = (const bf16x8*)Abuf + (size_t)tile * 512 + lane;

        bf16x8 ah[4], al[4];
        #pragma unroll
        for (int cc = 0; cc < 4; ++cc) {
            ah[cc] = At[cc * 128];
            al[cc] = At[cc * 128 + 64];
        }

        f32x4 acc0 = {0.f, 0.f, 0.f, 0.f}, acc1 = {0.f, 0.f, 0.f, 0.f};
        #pragma unroll
        for (int cc = 0; cc < 4; ++cc) {
            acc0 = __builtin_amdgcn_mfma_f32_16x16x32_bf16(ah[cc], bh[0][cc], acc0, 0, 0, 0);
            acc1 = __builtin_amdgcn_mfma_f32_16x16x32_bf16(ah[cc], bh[1][cc], acc1, 0, 0, 0);
            acc0 = __builtin_amdgcn_mfma_f32_16x16x32_bf16(al[cc], bh[0][cc], acc0, 0, 0, 0);
            acc1 = __builtin_amdgcn_mfma_f32_16x16x32_bf16(al[cc], bh[1][cc], acc1, 0, 0, 0);
            acc0 = __builtin_amdgcn_mfma_f32_16x16x32_bf16(ah[cc], bl[0][cc], acc0, 0, 0, 0);
            acc1 = __builtin_amdgcn_mfma_f32_16x16x32_bf16(ah[cc], bl[1][cc], acc1, 0, 0, 0);
        }

        const int rowb = m0 + 4 * g;
        #pragma unroll
        for (int r = 0; r < 4; ++r) {
            Hb[(size_t)(rowb + r) * FDIM + (t0 + 0) * 16 + r16] = f2bf(acc0[r]);
            Hb[(size_t)(rowb + r) * FDIM + (t0 + 1) * 16 + r16] = f2bf(acc1[r]);
        }

        if (wv == ((tile + rot) & 3)) {
            f32x4 acce = {0.f, 0.f, 0.f, 0.f};
            #pragma unroll
            for (int cc = 0; cc < 4; ++cc) {
                const bf16x8 bhe = *(const bf16x8*)(WThiE + cc * 32);
                const bf16x8 ble = *(const bf16x8*)(WTloE + cc * 32);
                acce = __builtin_amdgcn_mfma_f32_16x16x32_bf16(ah[cc], bhe, acce, 0, 0, 0);
                acce = __builtin_amdgcn_mfma_f32_16x16x32_bf16(al[cc], bhe, acce, 0, 0, 0);
                acce = __builtin_amdgcn_mfma_f32_16x16x32_bf16(ah[cc], ble, acce, 0, 0, 0);
            }
            if (r16 == 0) {
                #pragma unroll
                for (int r = 0; r < 4; ++r) asrcN[rowb + r] = acce[r];
            } else if (r16 == 1) {
                #pragma unroll
                for (int r = 0; r < 4; ++r) adstN[rowb + r] = acce[r];
            }
        }
    }
}

// ---------------- CSR build ----------------
__global__ void count_edges(const int* __restrict__ ei, int* __restrict__ cnt) {
    int i = blockIdx.x * 256 + threadIdx.x;
    if (i < EN_TOTAL) {
        int d = (i < N_EDGES) ? ei[N_EDGES + i] : (i - N_EDGES);
        atomicAdd(&cnt[d], 1);
    }
}

__global__ __launch_bounds__(256) void scan_block(const int* __restrict__ cnt,
                                                  int* __restrict__ off,
                                                  int* __restrict__ blockSums) {
    __shared__ int s[256];
    const int i = blockIdx.x * 256 + threadIdx.x;
    s[threadIdx.x] = (i < N_NODES) ? cnt[i] : 0;
    __syncthreads();
    #pragma unroll
    for (int d = 1; d < 256; d <<= 1) {
        int t = (threadIdx.x >= d) ? s[threadIdx.x - d] : 0;
        __syncthreads();
        s[threadIdx.x] += t;
        __syncthreads();
    }
    if (i < N_NODES) off[i + 1] = s[threadIdx.x];
    if (threadIdx.x == 255) blockSums[blockIdx.x] = s[255];
}

__global__ __launch_bounds__(256) void scan_sums(int* __restrict__ blockSums) {
    __shared__ int s[256];
    s[threadIdx.x] = (threadIdx.x < SCAN_NB) ? blockSums[threadIdx.x] : 0;
    __syncthreads();
    #pragma unroll
    for (int d = 1; d < 256; d <<= 1) {
        int t = (threadIdx.x >= d) ? s[threadIdx.x - d] : 0;
        __syncthreads();
        s[threadIdx.x] += t;
        __syncthreads();
    }
    if (threadIdx.x < SCAN_NB)
        blockSums[threadIdx.x] = (threadIdx.x == 0) ? 0 : s[threadIdx.x - 1];
}

__global__ __launch_bounds__(256) void add_base(int* __restrict__ off,
                                                const int* __restrict__ blockSums) {
    const int i = blockIdx.x * 256 + threadIdx.x;
    if (i < N_NODES) off[i + 1] += blockSums[blockIdx.x];
    if (i == 0) off[0] = 0;
}

__global__ void scatter_edges(const int* __restrict__ ei, const int* __restrict__ off,
                              int* __restrict__ cur, int* __restrict__ srcs) {
    int i = blockIdx.x * 256 + threadIdx.x;
    if (i < EN_TOTAL) {
        int s, d;
        if (i < N_EDGES) { s = ei[i]; d = ei[N_EDGES + i]; }
        else             { s = d = i - N_EDGES; }
        int p = off[d] + atomicAdd(&cur[d], 1);
        srcs[p] = s;
    }
}

// ---------------- segment softmax + weighted aggregation (bf16 H gather) -------
// After the shfl_xor butterfly ALL 64 lanes hold the reduced sums; the mode-0
// fragment write is spread across 32 lanes (fl x plane x jc), one uint4 each.
__global__ __launch_bounds__(256) void gat_aggregate(
    const unsigned short* __restrict__ Hb, const int* __restrict__ off,
    const int* __restrict__ srcs,
    const float* __restrict__ asrcN, const float* __restrict__ adstN,
    const float* __restrict__ bias,
    unsigned short* __restrict__ Abuf, float* __restrict__ OUTF, int mode)
{
    const int wave = threadIdx.x >> 6, lane = threadIdx.x & 63;
    const int grp = lane >> 3, fl = lane & 7;

    for (int n = blockIdx.x * 4 + wave; n < N_NODES; n += gridDim.x * 4) {
        const int s0 = off[n], s1 = off[n + 1];
        const int deg = s1 - s0;
        const float ad = adstN[n];

        float e_reg = -1e30f;
        float m = -1e30f;
        for (int j = s0 + lane; j < s1; j += 64) {
            float e = lrelu(asrcN[srcs[j]] + ad);
            if (j - s0 < 64) e_reg = e;
            m = fmaxf(m, e);
        }
        #pragma unroll
        for (int o = 32; o; o >>= 1) m = fmaxf(m, __shfl_xor(m, o));

        float4 a0 = {0,0,0,0}, a1 = {0,0,0,0}, a2 = {0,0,0,0}, a3 = {0,0,0,0};
        float dn = 0.f;
        const unsigned short* Hf = Hb + (size_t)fl * 16;
        for (int j = s0 + grp; j < s1; j += 8) {
            const int s = srcs[j];
            const float ex = (deg <= 64)
                ? __expf(__shfl(e_reg, j - s0) - m)
                : __expf(lrelu(asrcN[s] + ad) - m);
            dn += ex;
            const uint4* hp = (const uint4*)(Hf + (size_t)s * FDIM);
            const uint4 u0 = hp[0], u1 = hp[1];
            a0.x += ex * __uint_as_float(u0.x << 16);
            a0.y += ex * __uint_as_float(u0.x & 0xffff0000u);
            a0.z += ex * __uint_as_float(u0.y << 16);
            a0.w += ex * __uint_as_float(u0.y & 0xffff0000u);
            a1.x += ex * __uint_as_float(u0.z << 16);
            a1.y += ex * __uint_as_float(u0.z & 0xffff0000u);
            a1.z += ex * __uint_as_float(u0.w << 16);
            a1.w += ex * __uint_as_float(u0.w & 0xffff0000u);
            a2.x += ex * __uint_as_float(u1.x << 16);
            a2.y += ex * __uint_as_float(u1.x & 0xffff0000u);
            a2.z += ex * __uint_as_float(u1.y << 16);
            a2.w += ex * __uint_as_float(u1.y & 0xffff0000u);
            a3.x += ex * __uint_as_float(u1.z << 16);
            a3.y += ex * __uint_as_float(u1.z & 0xffff0000u);
            a3.z += ex * __uint_as_float(u1.w << 16);
            a3.w += ex * __uint_as_float(u1.w & 0xffff0000u);
        }

        #pragma unroll
        for (int o = 8; o <= 32; o <<= 1) {
            dn  += __shfl_xor(dn, o);
            a0.x += __shfl_xor(a0.x, o); a0.y += __shfl_xor(a0.y, o);
            a0.z += __shfl_xor(a0.z, o); a0.w += __shfl_xor(a0.w, o);
            a1.x += __shfl_xor(a1.x, o); a1.y += __shfl_xor(a1.y, o);
            a1.z += __shfl_xor(a1.z, o); a1.w += __shfl_xor(a1.w, o);
            a2.x += __shfl_xor(a2.x, o); a2.y += __shfl_xor(a2.y, o);
            a2.z += __shfl_xor(a2.z, o); a2.w += __shfl_xor(a2.w, o);
            a3.x += __shfl_xor(a3.x, o); a3.y += __shfl_xor(a3.y, o);
            a3.z += __shfl_xor(a3.z, o); a3.w += __shfl_xor(a3.w, o);
        }

        // biased (and relu'd for mode 0) outputs for my fl-slice — all lanes
        const float rd = 1.f / dn;
        const float4* bp = (const float4*)(bias + fl * 16);
        float4 o0, o1, o2, o3;
        {
            const float4 b0 = bp[0], b1 = bp[1], b2 = bp[2], b3 = bp[3];
            o0.x = a0.x * rd + b0.x; o0.y = a0.y * rd + b0.y;
            o0.z = a0.z * rd + b0.z; o0.w = a0.w * rd + b0.w;
            o1.x = a1.x * rd + b1.x; o1.y = a1.y * rd + b1.y;
            o1.z = a1.z * rd + b1.z; o1.w = a1.w * rd + b1.w;
            o2.x = a2.x * rd + b2.x; o2.y = a2.y * rd + b2.y;
            o2.z = a2.z * rd + b2.z; o2.w = a2.w * rd + b2.w;
            o3.x = a3.x * rd + b3.x; o3.y = a3.y * rd + b3.y;
            o3.z = a3.z * rd + b3.z; o3.w = a3.w * rd + b3.w;
        }

        if (mode == 1) {
            if (grp == 0) {
                float4* op = (float4*)(OUTF + (size_t)n * FDIM + fl * 16);
                op[0] = o0; op[1] = o1; op[2] = o2; op[3] = o3;
            }
        } else if (grp < 4) {
            // relu
            o0.x = fmaxf(o0.x, 0.f); o0.y = fmaxf(o0.y, 0.f);
            o0.z = fmaxf(o0.z, 0.f); o0.w = fmaxf(o0.w, 0.f);
            o1.x = fmaxf(o1.x, 0.f); o1.y = fmaxf(o1.y, 0.f);
            o1.z = fmaxf(o1.z, 0.f); o1.w = fmaxf(o1.w, 0.f);
            o2.x = fmaxf(o2.x, 0.f); o2.y = fmaxf(o2.y, 0.f);
            o2.z = fmaxf(o2.z, 0.f); o2.w = fmaxf(o2.w, 0.f);
            o3.x = fmaxf(o3.x, 0.f); o3.y = fmaxf(o3.y, 0.f);
            o3.z = fmaxf(o3.z, 0.f); o3.w = fmaxf(o3.w, 0.f);

            const int p = grp >> 1, jc = grp & 1;
            const float4 va = jc ? o2 : o0;
            const float4 vb = jc ? o3 : o1;
            const float v8[8] = {va.x, va.y, va.z, va.w, vb.x, vb.y, vb.z, vb.w};
            unsigned short out8[8];
            #pragma unroll
            for (int e = 0; e < 8; ++e) {
                const unsigned short h = f2bf(v8[e]);
                out8[e] = p ? f2bf(v8[e] - bf2f(h)) : h;
            }
            const int tile = n >> 4, r16n = n & 15, cc = fl >> 1;
            const int gslot = (fl & 1) * 2 + jc;
            const size_t base = ((size_t)(tile * 8 + cc * 2 + p) * 64 + gslot * 16 + r16n) * 8;
            *(uint4*)(Abuf + base) = *(const uint4*)out8;
        }
    }
}

// ---------------- global mean pool + final linear (8 rows in flight) ----------
__global__ __launch_bounds__(256) void pool_linear2(
    const float* __restrict__ H, const int* __restrict__ batch,
    const float* __restrict__ Wlin, const float* __restrict__ blin,
    float* __restrict__ out)
{
    const int g = blockIdx.x, tid = threadIdx.x;
    const int rl = tid >> 5, fq = tid & 31;

    int a = 0, b = N_NODES;
    while (a < b) { int mid = (a + b) >> 1; if (batch[mid] < g) a = mid + 1; else b = mid; }
    const int lo = a;
    b = N_NODES;
    while (a < b) { int mid = (a + b) >> 1; if (batch[mid] <= g) a = mid + 1; else b = mid; }
    const int hi = a;

    float4 acc = {0.f, 0.f, 0.f, 0.f};
    for (int n = lo + rl; n < hi; n += 8) {
        const float4 v = *(const float4*)(H + (size_t)n * FDIM + fq * 4);
        acc.x += v.x; acc.y += v.y; acc.z += v.z; acc.w += v.w;
    }
    __shared__ float4 s[8][32];
    s[rl][fq] = acc;
    __syncthreads();

    if (tid < 32) {
        float4 t = s[0][fq];
        #pragma unroll
        for (int r = 1; r < 8; ++r) {
            const float4 v = s[r][fq];
            t.x += v.x; t.y += v.y; t.z += v.z; t.w += v.w;
        }
        const float inv = 1.f / fmaxf((float)(hi - lo), 1.f);
        t.x *= inv; t.y *= inv; t.z *= inv; t.w *= inv;
        float d0 = t.x * Wlin[(fq * 4 + 0) * 2 + 0] + t.y * Wlin[(fq * 4 + 1) * 2 + 0]
                 + t.z * Wlin[(fq * 4 + 2) * 2 + 0] + t.w * Wlin[(fq * 4 + 3) * 2 + 0];
        float d1 = t.x * Wlin[(fq * 4 + 0) * 2 + 1] + t.y * Wlin[(fq * 4 + 1) * 2 + 1]
                 + t.z * Wlin[(fq * 4 + 2) * 2 + 1] + t.w * Wlin[(fq * 4 + 3) * 2 + 1];
        #pragma unroll
        for (int o = 1; o <= 16; o <<= 1) {
            d0 += __shfl_xor(d0, o);
            d1 += __shfl_xor(d1, o);
        }
        if (fq == 0) {
            out[g * 2 + 0] = d0 + blin[0];
            out[g * 2 + 1] = d1 + blin[1];
        }
    }
}

extern "C" void kernel_launch(void* const* d_in, const int* in_sizes, int n_in,
                              void* d_out, int out_size, void* d_ws, size_t ws_size,
                              hipStream_t stream)
{
    const float* x     = (const float*)d_in[0];
    const int*   ei    = (const int*)d_in[1];
    const int*   batch = (const int*)d_in[2];
    const float* W[3]    = {(const float*)d_in[3],  (const float*)d_in[7],  (const float*)d_in[11]};
    const float* avs[3]  = {(const float*)d_in[4],  (const float*)d_in[8],  (const float*)d_in[12]};
    const float* avd[3]  = {(const float*)d_in[5],  (const float*)d_in[9],  (const float*)d_in[13]};
    const float* bias[3] = {(const float*)d_in[6],  (const float*)d_in[10], (const float*)d_in[14]};
    const float* Wlin = (const float*)d_in[15];
    const float* blin = (const float*)d_in[16];
    float* out = (float*)d_out;

    char* w = (char*)d_ws;
    unsigned short* Abuf = (unsigned short*)w; w += (size_t)N_NODES * FDIM * 4; // 25.6 MB (hi+lo frag)
    float* hOf = (float*)Abuf;                                                  // overlay (pool input)
    unsigned short* Hb = (unsigned short*)w; w += (size_t)N_NODES * FDIM * 2;   // 12.8 MB
    float* attn  = (float*)w; w += 2 * 200192;
    int*   off   = (int*)w;   w += 200192;
    int*   cnt   = (int*)w;   w += 200192;
    int*   bsum  = (int*)w;   w += 4096;
    int*   srcs  = (int*)w;   w += (size_t)EN_TOTAL * 4;
    unsigned short* WT = (unsigned short*)w; w += (size_t)3 * 2 * WT_COLS * FDIM * 2;  // 221 KB
    float* asrcN = attn;
    float* adstN = attn + N_NODES;

    // ---- preps ----
    prep_planes<<<(GEMM_TILES * 4 * 64 + 255) / 256, 256, 0, stream>>>(x, Abuf);
    prep_wt<<<3, 256, 0, stream>>>(W[0], W[1], W[2],
                                   avs[0], avs[1], avs[2],
                                   avd[0], avd[1], avd[2], WT);

    // ---- CSR by destination (topology shared across layers) ----
    hipMemsetAsync(cnt, 0, N_NODES * sizeof(int), stream);
    count_edges<<<(EN_TOTAL + 255) / 256, 256, 0, stream>>>(ei, cnt);
    scan_block<<<SCAN_NB, 256, 0, stream>>>(cnt, off, bsum);
    scan_sums<<<1, 256, 0, stream>>>(bsum);
    add_base<<<SCAN_NB, 256, 0, stream>>>(off, bsum);
    hipMemsetAsync(cnt, 0, N_NODES * sizeof(int), stream);
    scatter_edges<<<(EN_TOTAL + 255) / 256, 256, 0, stream>>>(ei, off, cnt, srcs);

    // ---- 3 GAT layers ----
    for (int l = 0; l < 3; ++l) {
        const unsigned short* WThi = WT + (size_t)l * 2 * WT_COLS * FDIM;
        const unsigned short* WTlo = WThi + WT_COLS * FDIM;
        gemm_mfma5<<<1024, 256, 0, stream>>>(Abuf, WThi, WTlo, Hb, asrcN, adstN);
        gat_aggregate<<<2048, 256, 0, stream>>>(Hb, off, srcs, asrcN, adstN, bias[l],
                                                Abuf, hOf, (l < 2) ? 0 : 1);
    }

    // ---- mean pool + linear ----
    pool_linear2<<<N_GRAPHS, 256, 0, stream>>>(hOf, batch, Wlin, blin, out);
}

// Round 13
// 350.275 us; speedup vs baseline: 1.1111x; 1.0209x over previous
//
#include <hip/hip_runtime.h>
#include <math.h>

#define N_NODES  50000
#define N_EDGES  800000
#define FDIM     128
#define N_GRAPHS 500
#define NEG_SLOPE 0.2f
#define EN_TOTAL (N_EDGES + N_NODES)
#define SCAN_NB ((N_NODES + 255) / 256)   // 196
#define GEMM_TILES (N_NODES / 16)         // 3125 exact
#define WT_COLS 144                        // 128 + [wa_src, wa_dst, 14 zero]
#define PREP_PLANE_BLOCKS 1024
#define PREP_GRID (3 + PREP_PLANE_BLOCKS + SCAN_NB)

typedef short bf16x8 __attribute__((ext_vector_type(8)));
typedef float f32x4 __attribute__((ext_vector_type(4)));

static __device__ __forceinline__ float lrelu(float x) {
    return x >= 0.f ? x : NEG_SLOPE * x;
}
static __device__ __forceinline__ unsigned short f2bf(float v) {
    unsigned int u = __float_as_uint(v);
    u += 0x7fffu + ((u >> 16) & 1u);
    return (unsigned short)(u >> 16);
}
static __device__ __forceinline__ float bf2f(unsigned short s) {
    return __uint_as_float(((unsigned int)s) << 16);
}

// ---- fused prep: blocks 0-2 build WT (with attn extra cols); blocks 3..1026
//      split X into row-major bf16 hi/lo planes; blocks 1027+ zero cnt.
__global__ __launch_bounds__(256) void prep_all(
    const float* __restrict__ X,
    const float* __restrict__ W0, const float* __restrict__ W1,
    const float* __restrict__ W2,
    const float* __restrict__ as0, const float* __restrict__ as1,
    const float* __restrict__ as2,
    const float* __restrict__ ad0, const float* __restrict__ ad1,
    const float* __restrict__ ad2,
    unsigned short* __restrict__ WT,
    unsigned short* __restrict__ PHI, unsigned short* __restrict__ PLO,
    int* __restrict__ cnt)
{
    __shared__ float wa[256];
    const int b = blockIdx.x, tid = threadIdx.x;

    if (b < 3) {
        const float* W  = (b == 0) ? W0  : (b == 1) ? W1  : W2;
        const float* As = (b == 0) ? as0 : (b == 1) ? as1 : as2;
        const float* Ad = (b == 0) ? ad0 : (b == 1) ? ad1 : ad2;
        unsigned short* hi = WT + (size_t)b * 2 * WT_COLS * FDIM;
        unsigned short* lo = hi + WT_COLS * FDIM;
        {
            const int k = tid & 127;
            const float* av = (tid < 128) ? As : Ad;
            float s = 0.f;
            for (int c = 0; c < 128; ++c) s += W[k * FDIM + c] * av[c];
            wa[tid] = s;
        }
        __syncthreads();
        for (int i = tid; i < FDIM * FDIM; i += 256) {
            const int k = i >> 7, c = i & 127;
            const float v = W[i];
            const unsigned short h = f2bf(v);
            hi[c * FDIM + k] = h;
            lo[c * FDIM + k] = f2bf(v - bf2f(h));
        }
        for (int k = tid; k < FDIM; k += 256) {
            const float vs = wa[k], vd = wa[128 + k];
            const unsigned short hs = f2bf(vs), hd = f2bf(vd);
            hi[128 * FDIM + k] = hs; lo[128 * FDIM + k] = f2bf(vs - bf2f(hs));
            hi[129 * FDIM + k] = hd; lo[129 * FDIM + k] = f2bf(vd - bf2f(hd));
        }
        for (int i = tid; i < 14 * FDIM; i += 256) {
            hi[130 * FDIM + i] = 0;
            lo[130 * FDIM + i] = 0;
        }
    } else if (b < 3 + PREP_PLANE_BLOCKS) {
        const int total = N_NODES * FDIM / 4;
        for (int i = (b - 3) * 256 + tid; i < total; i += PREP_PLANE_BLOCKS * 256) {
            const float4 v = ((const float4*)X)[i];
            ushort4 h4, l4;
            h4.x = f2bf(v.x); l4.x = f2bf(v.x - bf2f(h4.x));
            h4.y = f2bf(v.y); l4.y = f2bf(v.y - bf2f(h4.y));
            h4.z = f2bf(v.z); l4.z = f2bf(v.z - bf2f(h4.z));
            h4.w = f2bf(v.w); l4.w = f2bf(v.w - bf2f(h4.w));
            ((ushort4*)PHI)[i] = h4;
            ((ushort4*)PLO)[i] = l4;
        }
    } else {
        const int i = (b - 3 - PREP_PLANE_BLOCKS) * 256 + tid;
        if (i < N_NODES) cnt[i] = 0;
    }
}

// ---------------- h = X @ W, persistent-B MFMA, LDS-staged shared A-tile ------
// 4 waves/block share one 16-row A-tile staged in LDS (double-buffered, 16KB).
// Stage: wave wv loads rows [4wv,4wv+4) coalesced (16B/lane) from row-major
// planes; LDS slot swizzled (slot ^= row&7) so fragment ds_read_b128 is
// bank-uniform. B frags persistent (as R12). Extra-duty attn tile unchanged.
__global__ __launch_bounds__(256) void gemm_mfma6(
    const unsigned short* __restrict__ PHI, const unsigned short* __restrict__ PLO,
    const unsigned short* __restrict__ WThi, const unsigned short* __restrict__ WTlo,
    unsigned short* __restrict__ Hb, float* __restrict__ asrcN, float* __restrict__ adstN)
{
    __shared__ unsigned short sH[2][16 * 128];
    __shared__ unsigned short sL[2][16 * 128];

    const int tid = threadIdx.x, wv = tid >> 6, lane = tid & 63;
    const int r16 = lane & 15, g = lane >> 4;
    const int t0 = wv * 2;

    bf16x8 bh[2][4], bl[2][4];
    #pragma unroll
    for (int tt = 0; tt < 2; ++tt) {
        const int c = (t0 + tt) * 16 + r16;
        #pragma unroll
        for (int cc = 0; cc < 4; ++cc) {
            bh[tt][cc] = *(const bf16x8*)(WThi + c * FDIM + cc * 32 + 8 * g);
            bl[tt][cc] = *(const bf16x8*)(WTlo + c * FDIM + cc * 32 + 8 * g);
        }
    }
    const unsigned short* WThiE = WThi + (128 + r16) * FDIM + 8 * g;
    const unsigned short* WTloE = WTlo + (128 + r16) * FDIM + 8 * g;

    // staging geometry: this lane stages row srow, logical 16B-slot sslot
    const int srow = wv * 4 + (lane >> 4);
    const int sslot = lane & 15;
    const int ldsOfs = srow * 128 + ((sslot ^ (srow & 7)) * 8);   // ushort units
    const size_t gOfs0 = (size_t)srow * FDIM + sslot * 8;

    int tile = blockIdx.x;
    {
        const size_t go = (size_t)tile * 16 * FDIM + gOfs0;
        *(uint4*)(&sH[0][ldsOfs]) = *(const uint4*)(PHI + go);
        *(uint4*)(&sL[0][ldsOfs]) = *(const uint4*)(PLO + go);
    }
    __syncthreads();

    int cur = 0, rot = 0;
    for (; tile < GEMM_TILES; tile += gridDim.x, ++rot) {
        const int nxt = tile + (int)gridDim.x;
        if (nxt < GEMM_TILES) {
            const size_t go = (size_t)nxt * 16 * FDIM + gOfs0;
            *(uint4*)(&sH[cur ^ 1][ldsOfs]) = *(const uint4*)(PHI + go);
            *(uint4*)(&sL[cur ^ 1][ldsOfs]) = *(const uint4*)(PLO + go);
        }

        bf16x8 ah[4], al[4];
        #pragma unroll
        for (int cc = 0; cc < 4; ++cc) {
            const int p = (cc * 4 + g) ^ (r16 & 7);
            const int ofs = r16 * 128 + p * 8;
            ah[cc] = *(const bf16x8*)(&sH[cur][ofs]);
            al[cc] = *(const bf16x8*)(&sL[cur][ofs]);
        }

        f32x4 acc0 = {0.f, 0.f, 0.f, 0.f}, acc1 = {0.f, 0.f, 0.f, 0.f};
        #pragma unroll
        for (int cc = 0; cc < 4; ++cc) {
            acc0 = __builtin_amdgcn_mfma_f32_16x16x32_bf16(ah[cc], bh[0][cc], acc0, 0, 0, 0);
            acc1 = __builtin_amdgcn_mfma_f32_16x16x32_bf16(ah[cc], bh[1][cc], acc1, 0, 0, 0);
            acc0 = __builtin_amdgcn_mfma_f32_16x16x32_bf16(al[cc], bh[0][cc], acc0, 0, 0, 0);
            acc1 = __builtin_amdgcn_mfma_f32_16x16x32_bf16(al[cc], bh[1][cc], acc1, 0, 0, 0);
            acc0 = __builtin_amdgcn_mfma_f32_16x16x32_bf16(ah[cc], bl[0][cc], acc0, 0, 0, 0);
            acc1 = __builtin_amdgcn_mfma_f32_16x16x32_bf16(ah[cc], bl[1][cc], acc1, 0, 0, 0);
        }

        const int m0 = tile * 16;
        const int rowb = m0 + 4 * g;
        #pragma unroll
        for (int r = 0; r < 4; ++r) {
            Hb[(size_t)(rowb + r) * FDIM + (t0 + 0) * 16 + r16] = f2bf(acc0[r]);
            Hb[(size_t)(rowb + r) * FDIM + (t0 + 1) * 16 + r16] = f2bf(acc1[r]);
        }

        if (wv == ((tile + rot) & 3)) {
            f32x4 acce = {0.f, 0.f, 0.f, 0.f};
            #pragma unroll
            for (int cc = 0; cc < 4; ++cc) {
                const bf16x8 bhe = *(const bf16x8*)(WThiE + cc * 32);
                const bf16x8 ble = *(const bf16x8*)(WTloE + cc * 32);
                acce = __builtin_amdgcn_mfma_f32_16x16x32_bf16(ah[cc], bhe, acce, 0, 0, 0);
                acce = __builtin_amdgcn_mfma_f32_16x16x32_bf16(al[cc], bhe, acce, 0, 0, 0);
                acce = __builtin_amdgcn_mfma_f32_16x16x32_bf16(ah[cc], ble, acce, 0, 0, 0);
            }
            if (r16 == 0) {
                #pragma unroll
                for (int r = 0; r < 4; ++r) asrcN[rowb + r] = acce[r];
            } else if (r16 == 1) {
                #pragma unroll
                for (int r = 0; r < 4; ++r) adstN[rowb + r] = acce[r];
            }
        }

        __syncthreads();
        cur ^= 1;
    }
}

// ---------------- CSR build ----------------
__global__ void count_edges(const int* __restrict__ ei, int* __restrict__ cnt) {
    int i = blockIdx.x * 256 + threadIdx.x;
    if (i < EN_TOTAL) {
        int d = (i < N_EDGES) ? ei[N_EDGES + i] : (i - N_EDGES);
        atomicAdd(&cnt[d], 1);
    }
}

__global__ __launch_bounds__(256) void scan_block(const int* __restrict__ cnt,
                                                  int* __restrict__ off,
                                                  int* __restrict__ blockSums) {
    __shared__ int s[256];
    const int i = blockIdx.x * 256 + threadIdx.x;
    s[threadIdx.x] = (i < N_NODES) ? cnt[i] : 0;
    __syncthreads();
    #pragma unroll
    for (int d = 1; d < 256; d <<= 1) {
        int t = (threadIdx.x >= d) ? s[threadIdx.x - d] : 0;
        __syncthreads();
        s[threadIdx.x] += t;
        __syncthreads();
    }
    if (i < N_NODES) off[i + 1] = s[threadIdx.x];
    if (threadIdx.x == 255) blockSums[blockIdx.x] = s[255];
}

__global__ __launch_bounds__(256) void scan_sums(int* __restrict__ blockSums) {
    __shared__ int s[256];
    s[threadIdx.x] = (threadIdx.x < SCAN_NB) ? blockSums[threadIdx.x] : 0;
    __syncthreads();
    #pragma unroll
    for (int d = 1; d < 256; d <<= 1) {
        int t = (threadIdx.x >= d) ? s[threadIdx.x - d] : 0;
        __syncthreads();
        s[threadIdx.x] += t;
        __syncthreads();
    }
    if (threadIdx.x < SCAN_NB)
        blockSums[threadIdx.x] = (threadIdx.x == 0) ? 0 : s[threadIdx.x - 1];
}

// also writes the mutable copy offm (scatter's atomic cursor) -> no memset
__global__ __launch_bounds__(256) void add_base(int* __restrict__ off,
                                                const int* __restrict__ blockSums,
                                                int* __restrict__ offm) {
    const int i = blockIdx.x * 256 + threadIdx.x;
    if (i < N_NODES) {
        const int v = off[i + 1] + blockSums[blockIdx.x];
        off[i + 1] = v;
        offm[i + 1] = v;
    }
    if (i == 0) { off[0] = 0; offm[0] = 0; }
}

__global__ void scatter_edges(const int* __restrict__ ei, int* __restrict__ offm,
                              int* __restrict__ srcs) {
    int i = blockIdx.x * 256 + threadIdx.x;
    if (i < EN_TOTAL) {
        int s, d;
        if (i < N_EDGES) { s = ei[i]; d = ei[N_EDGES + i]; }
        else             { s = d = i - N_EDGES; }
        int p = atomicAdd(&offm[d], 1);
        srcs[p] = s;
    }
}

// ---------------- segment softmax + weighted aggregation (R10-exact writer) ----
__global__ __launch_bounds__(256) void gat_aggregate(
    const unsigned short* __restrict__ Hb, const int* __restrict__ off,
    const int* __restrict__ srcs,
    const float* __restrict__ asrcN, const float* __restrict__ adstN,
    const float* __restrict__ bias,
    unsigned short* __restrict__ PHI, unsigned short* __restrict__ PLO,
    float* __restrict__ OUTF, int mode)
{
    const int wave = threadIdx.x >> 6, lane = threadIdx.x & 63;
    const int grp = lane >> 3, fl = lane & 7;

    for (int n = blockIdx.x * 4 + wave; n < N_NODES; n += gridDim.x * 4) {
        const int s0 = off[n], s1 = off[n + 1];
        const int deg = s1 - s0;
        const float ad = adstN[n];

        float e_reg = -1e30f;
        float m = -1e30f;
        for (int j = s0 + lane; j < s1; j += 64) {
            float e = lrelu(asrcN[srcs[j]] + ad);
            if (j - s0 < 64) e_reg = e;
            m = fmaxf(m, e);
        }
        #pragma unroll
        for (int o = 32; o; o >>= 1) m = fmaxf(m, __shfl_xor(m, o));

        float4 a0 = {0,0,0,0}, a1 = {0,0,0,0}, a2 = {0,0,0,0}, a3 = {0,0,0,0};
        float dn = 0.f;
        const unsigned short* Hf = Hb + (size_t)fl * 16;
        for (int j = s0 + grp; j < s1; j += 8) {
            const int s = srcs[j];
            const float ex = (deg <= 64)
                ? __expf(__shfl(e_reg, j - s0) - m)
                : __expf(lrelu(asrcN[s] + ad) - m);
            dn += ex;
            const uint4* hp = (const uint4*)(Hf + (size_t)s * FDIM);
            const uint4 u0 = hp[0], u1 = hp[1];
            a0.x += ex * __uint_as_float(u0.x << 16);
            a0.y += ex * __uint_as_float(u0.x & 0xffff0000u);
            a0.z += ex * __uint_as_float(u0.y << 16);
            a0.w += ex * __uint_as_float(u0.y & 0xffff0000u);
            a1.x += ex * __uint_as_float(u0.z << 16);
            a1.y += ex * __uint_as_float(u0.z & 0xffff0000u);
            a1.z += ex * __uint_as_float(u0.w << 16);
            a1.w += ex * __uint_as_float(u0.w & 0xffff0000u);
            a2.x += ex * __uint_as_float(u1.x << 16);
            a2.y += ex * __uint_as_float(u1.x & 0xffff0000u);
            a2.z += ex * __uint_as_float(u1.y << 16);
            a2.w += ex * __uint_as_float(u1.y & 0xffff0000u);
            a3.x += ex * __uint_as_float(u1.z << 16);
            a3.y += ex * __uint_as_float(u1.z & 0xffff0000u);
            a3.z += ex * __uint_as_float(u1.w << 16);
            a3.w += ex * __uint_as_float(u1.w & 0xffff0000u);
        }

        #pragma unroll
        for (int o = 8; o <= 32; o <<= 1) {
            dn  += __shfl_xor(dn, o);
            a0.x += __shfl_xor(a0.x, o); a0.y += __shfl_xor(a0.y, o);
            a0.z += __shfl_xor(a0.z, o); a0.w += __shfl_xor(a0.w, o);
            a1.x += __shfl_xor(a1.x, o); a1.y += __shfl_xor(a1.y, o);
            a1.z += __shfl_xor(a1.z, o); a1.w += __shfl_xor(a1.w, o);
            a2.x += __shfl_xor(a2.x, o); a2.y += __shfl_xor(a2.y, o);
            a2.z += __shfl_xor(a2.z, o); a2.w += __shfl_xor(a2.w, o);
            a3.x += __shfl_xor(a3.x, o); a3.y += __shfl_xor(a3.y, o);
            a3.z += __shfl_xor(a3.z, o); a3.w += __shfl_xor(a3.w, o);
        }

        if (grp == 0) {
            const float rd = 1.f / dn;
            const float4* bp = (const float4*)(bias + fl * 16);
            float4 ov[4] = {a0, a1, a2, a3};
            #pragma unroll
            for (int q = 0; q < 4; ++q) {
                const float4 b4 = bp[q];
                float4 o4;
                o4.x = ov[q].x * rd + b4.x; o4.y = ov[q].y * rd + b4.y;
                o4.z = ov[q].z * rd + b4.z; o4.w = ov[q].w * rd + b4.w;
                if (mode == 0) {
                    o4.x = fmaxf(o4.x, 0.f); o4.y = fmaxf(o4.y, 0.f);
                    o4.z = fmaxf(o4.z, 0.f); o4.w = fmaxf(o4.w, 0.f);
                    ushort4 h4, l4;
                    h4.x = f2bf(o4.x); l4.x = f2bf(o4.x - bf2f(h4.x));
                    h4.y = f2bf(o4.y); l4.y = f2bf(o4.y - bf2f(h4.y));
                    h4.z = f2bf(o4.z); l4.z = f2bf(o4.z - bf2f(h4.z));
                    h4.w = f2bf(o4.w); l4.w = f2bf(o4.w - bf2f(h4.w));
                    const size_t base = (size_t)n * FDIM + fl * 16 + q * 4;
                    *(ushort4*)(PHI + base) = h4;
                    *(ushort4*)(PLO + base) = l4;
                } else {
                    *(float4*)(OUTF + (size_t)n * FDIM + fl * 16 + q * 4) = o4;
                }
            }
        }
    }
}

// ---------------- global mean pool + final linear (8 rows in flight) ----------
__global__ __launch_bounds__(256) void pool_linear2(
    const float* __restrict__ H, const int* __restrict__ batch,
    const float* __restrict__ Wlin, const float* __restrict__ blin,
    float* __restrict__ out)
{
    const int g = blockIdx.x, tid = threadIdx.x;
    const int rl = tid >> 5, fq = tid & 31;

    int a = 0, b = N_NODES;
    while (a < b) { int mid = (a + b) >> 1; if (batch[mid] < g) a = mid + 1; else b = mid; }
    const int lo = a;
    b = N_NODES;
    while (a < b) { int mid = (a + b) >> 1; if (batch[mid] <= g) a = mid + 1; else b = mid; }
    const int hi = a;

    float4 acc = {0.f, 0.f, 0.f, 0.f};
    for (int n = lo + rl; n < hi; n += 8) {
        const float4 v = *(const float4*)(H + (size_t)n * FDIM + fq * 4);
        acc.x += v.x; acc.y += v.y; acc.z += v.z; acc.w += v.w;
    }
    __shared__ float4 s[8][32];
    s[rl][fq] = acc;
    __syncthreads();

    if (tid < 32) {
        float4 t = s[0][fq];
        #pragma unroll
        for (int r = 1; r < 8; ++r) {
            const float4 v = s[r][fq];
            t.x += v.x; t.y += v.y; t.z += v.z; t.w += v.w;
        }
        const float inv = 1.f / fmaxf((float)(hi - lo), 1.f);
        t.x *= inv; t.y *= inv; t.z *= inv; t.w *= inv;
        float d0 = t.x * Wlin[(fq * 4 + 0) * 2 + 0] + t.y * Wlin[(fq * 4 + 1) * 2 + 0]
                 + t.z * Wlin[(fq * 4 + 2) * 2 + 0] + t.w * Wlin[(fq * 4 + 3) * 2 + 0];
        float d1 = t.x * Wlin[(fq * 4 + 0) * 2 + 1] + t.y * Wlin[(fq * 4 + 1) * 2 + 1]
                 + t.z * Wlin[(fq * 4 + 2) * 2 + 1] + t.w * Wlin[(fq * 4 + 3) * 2 + 1];
        #pragma unroll
        for (int o = 1; o <= 16; o <<= 1) {
            d0 += __shfl_xor(d0, o);
            d1 += __shfl_xor(d1, o);
        }
        if (fq == 0) {
            out[g * 2 + 0] = d0 + blin[0];
            out[g * 2 + 1] = d1 + blin[1];
        }
    }
}

extern "C" void kernel_launch(void* const* d_in, const int* in_sizes, int n_in,
                              void* d_out, int out_size, void* d_ws, size_t ws_size,
                              hipStream_t stream)
{
    const float* x     = (const float*)d_in[0];
    const int*   ei    = (const int*)d_in[1];
    const int*   batch = (const int*)d_in[2];
    const float* W[3]    = {(const float*)d_in[3],  (const float*)d_in[7],  (const float*)d_in[11]};
    const float* avs[3]  = {(const float*)d_in[4],  (const float*)d_in[8],  (const float*)d_in[12]};
    const float* avd[3]  = {(const float*)d_in[5],  (const float*)d_in[9],  (const float*)d_in[13]};
    const float* bias[3] = {(const float*)d_in[6],  (const float*)d_in[10], (const float*)d_in[14]};
    const float* Wlin = (const float*)d_in[15];
    const float* blin = (const float*)d_in[16];
    float* out = (float*)d_out;

    char* w = (char*)d_ws;
    unsigned short* PHI = (unsigned short*)w; w += (size_t)N_NODES * FDIM * 2;  // 12.8 MB
    unsigned short* PLO = (unsigned short*)w; w += (size_t)N_NODES * FDIM * 2;  // 12.8 MB
    float* hOf = (float*)PHI;                                                   // overlay (25.6MB span)
    unsigned short* Hb = (unsigned short*)w; w += (size_t)N_NODES * FDIM * 2;   // 12.8 MB
    float* attn  = (float*)w; w += 2 * 200192;
    int*   off   = (int*)w;   w += 200192;
    int*   offm  = (int*)w;   w += 200192;                                      // mutable cursor copy
    int*   cnt   = (int*)w;   w += 200192;
    int*   bsum  = (int*)w;   w += 4096;
    int*   srcs  = (int*)w;   w += (size_t)EN_TOTAL * 4;
    unsigned short* WT = (unsigned short*)w; w += (size_t)3 * 2 * WT_COLS * FDIM * 2;  // 221 KB
    float* asrcN = attn;
    float* adstN = attn + N_NODES;

    // ---- fused prep (WT + planes + cnt zero) ----
    prep_all<<<PREP_GRID, 256, 0, stream>>>(x, W[0], W[1], W[2],
                                            avs[0], avs[1], avs[2],
                                            avd[0], avd[1], avd[2],
                                            WT, PHI, PLO, cnt);

    // ---- CSR by destination (topology shared across layers) ----
    count_edges<<<(EN_TOTAL + 255) / 256, 256, 0, stream>>>(ei, cnt);
    scan_block<<<SCAN_NB, 256, 0, stream>>>(cnt, off, bsum);
    scan_sums<<<1, 256, 0, stream>>>(bsum);
    add_base<<<SCAN_NB, 256, 0, stream>>>(off, bsum, offm);
    scatter_edges<<<(EN_TOTAL + 255) / 256, 256, 0, stream>>>(ei, offm, srcs);

    // ---- 3 GAT layers ----
    for (int l = 0; l < 3; ++l) {
        const unsigned short* WThi = WT + (size_t)l * 2 * WT_COLS * FDIM;
        const unsigned short* WTlo = WThi + WT_COLS * FDIM;
        gemm_mfma6<<<1024, 256, 0, stream>>>(PHI, PLO, WThi, WTlo, Hb, asrcN, adstN);
        gat_aggregate<<<2048, 256, 0, stream>>>(Hb, off, srcs, asrcN, adstN, bias[l],
                                                PHI, PLO, hOf, (l < 2) ? 0 : 1);
    }

    // ---- mean pool + linear ----
    pool_linear2<<<N_GRAPHS, 256, 0, stream>>>(hOf, batch, Wlin, blin, out);
}